// Round 1
// baseline (110.024 us; speedup 1.0000x reference)
//
#include <hip/hip_runtime.h>

// TriAffine: S[b,x,y,z] = sum_{i,k,j} xb[b,x,i] z[b,z,k] W[i,k,j] yb[b,y,j]
// B=2, L=256, N_IN=128. Output [2,256,256,256] f32 (134 MB).
//
// 3-stage bf16 MFMA pipeline:
//  prep  : x,y,z f32 -> bf16 (ws)
//  stage1: A2[bx,k,j] = sum_i x*W + W[128,k,j]        (bf16, ws, j-stride 152)
//  stage2: per (b,x): P'[k,y] = sum_j A2*y + A2[k,128]; S[y,z] = sum_k z*P'
//          P' stays in registers: 16x16x32 C-layout == 16x16x16 B-operand layout.

typedef __bf16 bf16x8 __attribute__((ext_vector_type(8)));
typedef short short4_t __attribute__((ext_vector_type(4)));
typedef float f32x4 __attribute__((ext_vector_type(4)));
typedef unsigned short ushort4_t __attribute__((ext_vector_type(4)));

#define LL 256
#define NI 128
#define NBX 512
#define A2_STRIDE 152                  // padded j-stride (bf16): 304B rows, 16B aligned, 2-way banks
#define A2_PER_BX (128 * A2_STRIDE)    // 19456 elems per bx

__device__ __forceinline__ unsigned short f2bf(float f) {
    unsigned u = __builtin_bit_cast(unsigned, f);
    u += 0x7FFFu + ((u >> 16) & 1u);   // RNE
    return (unsigned short)(u >> 16);
}
__device__ __forceinline__ float bf2f(unsigned short h) {
    return __builtin_bit_cast(float, (unsigned)h << 16);
}

// ---------------- prep: f32 -> bf16 for x,y,z (each 65536 elems) ----------------
__global__ __launch_bounds__(256) void prep_kernel(const float* __restrict__ x,
                                                   const float* __restrict__ y,
                                                   const float* __restrict__ z,
                                                   unsigned short* __restrict__ dst) {
    int t = blockIdx.x * 256 + threadIdx.x;      // 0..49151
    int base = t * 4;
    int which = base >> 16;                      // 0,1,2
    int local = base & 65535;
    const float* s = (which == 0) ? x : (which == 1) ? y : z;
    float4 v = *(const float4*)(s + local);
    ushort4_t o;
    o[0] = f2bf(v.x); o[1] = f2bf(v.y); o[2] = f2bf(v.z); o[3] = f2bf(v.w);
    *(ushort4_t*)(dst + base) = o;
}

// ---------------- stage1: A2[bx][k][j] = sum_{i<128} x[bx,i] W[i,k,j] + W[128,k,j] ----------------
// grid (128 k, 4 bx-groups of 128), 256 threads (4 waves, wave owns 32 bx rows).
// D[j, bx] tiles: A-op = WkT rows j (from LDS, i-consecutive), B-op = x rows bx.
__global__ __launch_bounds__(256) void stage1_kernel(const float* __restrict__ W,
                                                     const unsigned short* __restrict__ xbf,
                                                     unsigned short* __restrict__ A2g) {
    const int k   = blockIdx.x;
    const int bxg = blockIdx.y;
    const int tid = threadIdx.x;
    const int wv = tid >> 6, lane = tid & 63;
    const int l15 = lane & 15, h = lane >> 4;

    __shared__ unsigned short wkT[16 * A2_STRIDE];   // [jj][i], i in 0..128 (i=128 = bias row)

    // preload X fragments: rows bx, 8 consecutive i per lane
    const int bx0 = bxg * 128 + wv * 32;
    bf16x8 xf[2][4];
#pragma unroll
    for (int bxt = 0; bxt < 2; ++bxt)
#pragma unroll
        for (int is = 0; is < 4; ++is)
            xf[bxt][is] = *(const bf16x8*)(xbf + (bx0 + bxt * 16 + l15) * NI + is * 32 + 8 * h);

    for (int jt = 0; jt < 9; ++jt) {
        const int j0 = jt * 16;
        __syncthreads();   // previous iter's LDS reads done
        for (int idx = tid; idx < 129 * 16; idx += 256) {
            int i = idx >> 4, jj = idx & 15, j = j0 + jj;
            float v = (j < 129) ? W[(i * 128 + k) * 129 + j] : 0.f;
            wkT[jj * A2_STRIDE + i] = f2bf(v);
        }
        __syncthreads();

        f32x4 acc[2];
#pragma unroll
        for (int r = 0; r < 4; ++r) {            // bias init: + W[128,k,j]
            float bv = bf2f(wkT[(4 * h + r) * A2_STRIDE + 128]);
            acc[0][r] = bv; acc[1][r] = bv;
        }
#pragma unroll
        for (int is = 0; is < 4; ++is) {
            bf16x8 wf = *(const bf16x8*)&wkT[l15 * A2_STRIDE + is * 32 + 8 * h];
            acc[0] = __builtin_amdgcn_mfma_f32_16x16x32_bf16(wf, xf[0][is], acc[0], 0, 0, 0);
            acc[1] = __builtin_amdgcn_mfma_f32_16x16x32_bf16(wf, xf[1][is], acc[1], 0, 0, 0);
        }
        // store: lane holds j = j0+4h+reg (consecutive), bx = col
#pragma unroll
        for (int bxt = 0; bxt < 2; ++bxt) {
            int bx = bx0 + bxt * 16 + l15;
            unsigned short* dst = A2g + bx * A2_PER_BX + k * A2_STRIDE;
            if (jt < 8) {
                ushort4_t o;
#pragma unroll
                for (int r = 0; r < 4; ++r) o[r] = f2bf(acc[bxt][r]);
                *(ushort4_t*)(dst + j0 + 4 * h) = o;
            } else if (h == 0) {
                dst[128] = f2bf(acc[bxt][0]);    // j == 128 (bias column for stage 2)
            }
        }
    }
}

// ---------------- stage2: per (b,x) block -> S[y,z] 256x256 ----------------
// 8 waves (512 thr); wave owns 32 y rows.
// Phase A: P'[k,y] = sum_{j<128} A2[k,j]*y[b,y,j] + A2[k,128]   (16x16x32)
// Phase B: S[y,z]  = sum_k z[b,z,k]*P'[k,y]                      (16x16x16, P' in regs)
__global__ __launch_bounds__(512) void stage2_kernel(const unsigned short* __restrict__ ybf,
                                                     const unsigned short* __restrict__ zbf,
                                                     const unsigned short* __restrict__ A2g,
                                                     float* __restrict__ out) {
    const int bx  = blockIdx.x;            // b*256 + x
    const int b   = bx >> 8;
    const int tid = threadIdx.x;
    const int wv = tid >> 6, lane = tid & 63;
    const int l15 = lane & 15, h = lane >> 4;

    __shared__ unsigned short A2s[128 * A2_STRIDE];   // 38912 B

    {   // stage A2[bx] into LDS (16B chunks)
        const float4* src = (const float4*)(A2g + bx * A2_PER_BX);
        float4* dstl = (float4*)A2s;
        for (int t = tid; t < A2_PER_BX / 8; t += 512) dstl[t] = src[t];
    }
    __syncthreads();

    const int y0 = wv * 32;
    const unsigned short* yb = ybf + b * LL * NI;
    const unsigned short* zb = zbf + b * LL * NI;

    // ---- Phase A ----
    f32x4 accP[8][2];                      // [k-tile][y-tile]
#pragma unroll
    for (int kt = 0; kt < 8; ++kt)
#pragma unroll
        for (int r = 0; r < 4; ++r) {      // bias init: + A2[k,128]
            float bias = bf2f(A2s[(kt * 16 + 4 * h + r) * A2_STRIDE + 128]);
            accP[kt][0][r] = bias; accP[kt][1][r] = bias;
        }
#pragma unroll
    for (int js = 0; js < 4; ++js) {
        bf16x8 yf[2];
#pragma unroll
        for (int yt = 0; yt < 2; ++yt)
            yf[yt] = *(const bf16x8*)(yb + (y0 + yt * 16 + l15) * NI + js * 32 + 8 * h);
#pragma unroll
        for (int kt = 0; kt < 8; ++kt) {
            bf16x8 af = *(const bf16x8*)&A2s[(kt * 16 + l15) * A2_STRIDE + js * 32 + 8 * h];
            accP[kt][0] = __builtin_amdgcn_mfma_f32_16x16x32_bf16(af, yf[0], accP[kt][0], 0, 0, 0);
            accP[kt][1] = __builtin_amdgcn_mfma_f32_16x16x32_bf16(af, yf[1], accP[kt][1], 0, 0, 0);
        }
    }

    // ---- convert P' to 16x16x16 B-operand frags (layout matches C-layout exactly) ----
    short4_t pf[8][2];
#pragma unroll
    for (int kt = 0; kt < 8; ++kt)
#pragma unroll
        for (int yt = 0; yt < 2; ++yt)
#pragma unroll
            for (int r = 0; r < 4; ++r)
                pf[kt][yt][r] = (short)f2bf(accP[kt][yt][r]);

    // ---- Phase B ----
    float* outb = out + bx * (LL * LL);
#pragma unroll 1
    for (int zt = 0; zt < 16; ++zt) {
        f32x4 acc2[2];
#pragma unroll
        for (int yt = 0; yt < 2; ++yt) { acc2[yt][0] = 0.f; acc2[yt][1] = 0.f; acc2[yt][2] = 0.f; acc2[yt][3] = 0.f; }
#pragma unroll
        for (int kt = 0; kt < 8; ++kt) {
            short4_t zf = *(const short4_t*)(zb + (zt * 16 + l15) * NI + kt * 16 + 4 * h);
            acc2[0] = __builtin_amdgcn_mfma_f32_16x16x16bf16_1k(zf, pf[kt][0], acc2[0], 0, 0, 0);
            acc2[1] = __builtin_amdgcn_mfma_f32_16x16x16bf16_1k(zf, pf[kt][1], acc2[1], 0, 0, 0);
        }
        // D[z,y]: z = zt*16 + 4h + reg (consecutive) -> one dwordx4 per lane per y-tile
#pragma unroll
        for (int yt = 0; yt < 2; ++yt) {
            int y = y0 + yt * 16 + l15;
            *(f32x4*)(outb + y * LL + zt * 16 + 4 * h) = acc2[yt];
        }
    }
}

extern "C" void kernel_launch(void* const* d_in, const int* in_sizes, int n_in,
                              void* d_out, int out_size, void* d_ws, size_t ws_size,
                              hipStream_t stream) {
    const float* x = (const float*)d_in[0];
    const float* y = (const float*)d_in[1];
    const float* z = (const float*)d_in[2];
    const float* W = (const float*)d_in[3];   // [129][128][129][1]
    float* out = (float*)d_out;

    unsigned short* xbf = (unsigned short*)d_ws;     // 65536
    unsigned short* ybf = xbf + 65536;               // 65536
    unsigned short* zbf = ybf + 65536;               // 65536
    unsigned short* A2g = zbf + 65536;               // 512 * 19456 elems (~19.9 MB)

    prep_kernel<<<192, 256, 0, stream>>>(x, y, z, xbf);
    stage1_kernel<<<dim3(128, 4), 256, 0, stream>>>(W, xbf, A2g);
    stage2_kernel<<<NBX, 512, 0, stream>>>(ybf, zbf, A2g, out);
}